// Round 1
// baseline (8594.370 us; speedup 1.0000x reference)
//
#include <hip/hip_runtime.h>
#include <math.h>

#define B_ 32
#define T_ 512
#define U_ 64
#define V_ 32000
#define H_ 512
#define E_ 512

// ---------------- embedding gather: embedded[b,u,:] = emb_table[tok[b,u]] ----------------
__global__ void embed_kernel(const int* __restrict__ tok, const float* __restrict__ table,
                             float* __restrict__ out) {
  int row = blockIdx.x;                    // b*U + u
  int t = tok[row];
  const float4* src = (const float4*)(table + (size_t)t * H_);
  float4* dst = (float4*)(out + (size_t)row * H_);
  dst[threadIdx.x] = src[threadIdx.x];     // 128 threads * 4 floats = 512
}

__global__ void zero_kernel(float* p, int n) {
  int i = blockIdx.x * blockDim.x + threadIdx.x;
  if (i < n) p[i] = 0.f;
}

// ---------------- fp32 GEMM: C[m,n] = sum_k A[m,K]*Bm[n,K] + bias[n] ----------------
// 128x128 tile, BK=8, 256 threads, 8x8 per thread. M = gridDim.y*128, N = gridDim.x*128.
__global__ __launch_bounds__(256) void gemm_abt(
    const float* __restrict__ A, const float* __restrict__ Bm,
    const float* __restrict__ bias, float* __restrict__ C, int N, int K) {
  __shared__ float As[8][128];
  __shared__ float Bs[8][128];
  int tid = threadIdx.x;
  int n0 = blockIdx.x * 128, m0 = blockIdx.y * 128;
  int lr = tid >> 1;            // 0..127: tile row being loaded
  int lk = (tid & 1) * 4;       // k sub-offset 0 or 4
  const float* Ap = A + (size_t)(m0 + lr) * K + lk;
  const float* Bp = Bm + (size_t)(n0 + lr) * K + lk;
  int tx = tid & 15, ty = tid >> 4;
  float acc[8][8];
#pragma unroll
  for (int i = 0; i < 8; i++)
#pragma unroll
    for (int j = 0; j < 8; j++) acc[i][j] = 0.f;

  for (int k0 = 0; k0 < K; k0 += 8) {
    float4 av = *(const float4*)(Ap + k0);
    float4 bv = *(const float4*)(Bp + k0);
    __syncthreads();
    As[lk + 0][lr] = av.x; As[lk + 1][lr] = av.y; As[lk + 2][lr] = av.z; As[lk + 3][lr] = av.w;
    Bs[lk + 0][lr] = bv.x; Bs[lk + 1][lr] = bv.y; Bs[lk + 2][lr] = bv.z; Bs[lk + 3][lr] = bv.w;
    __syncthreads();
#pragma unroll
    for (int kk = 0; kk < 8; kk++) {
      float a[8], b[8];
      *(float4*)&a[0] = *(const float4*)&As[kk][ty * 4];
      *(float4*)&a[4] = *(const float4*)&As[kk][ty * 4 + 64];
      *(float4*)&b[0] = *(const float4*)&Bs[kk][tx * 4];
      *(float4*)&b[4] = *(const float4*)&Bs[kk][tx * 4 + 64];
#pragma unroll
      for (int i = 0; i < 8; i++)
#pragma unroll
        for (int j = 0; j < 8; j++) acc[i][j] = fmaf(a[i], b[j], acc[i][j]);
    }
  }
  float bb[8] = {0, 0, 0, 0, 0, 0, 0, 0};
  if (bias) {
    *(float4*)&bb[0] = *(const float4*)&bias[n0 + tx * 4];
    *(float4*)&bb[4] = *(const float4*)&bias[n0 + tx * 4 + 64];
  }
#pragma unroll
  for (int i = 0; i < 8; i++) {
    int m = m0 + ty * 4 + (i & 3) + (i >> 2) * 64;
    float* Crow = C + (size_t)m * N + n0;
    float4 o0 = make_float4(acc[i][0] + bb[0], acc[i][1] + bb[1], acc[i][2] + bb[2], acc[i][3] + bb[3]);
    float4 o1 = make_float4(acc[i][4] + bb[4], acc[i][5] + bb[5], acc[i][6] + bb[6], acc[i][7] + bb[7]);
    *(float4*)(Crow + tx * 4) = o0;
    *(float4*)(Crow + tx * 4 + 64) = o1;
  }
}

// ---------------- per-step attention: scores -> softmax -> context -> X[:,512:1024] ----------------
__global__ __launch_bounds__(512) void attn_step(
    const float* __restrict__ enc_proj, const float* __restrict__ enc_out,
    const int* __restrict__ lens, const float* __restrict__ embedded,
    const float* __restrict__ h1_prev, float* __restrict__ X, int u) {
  int b = blockIdx.x;
  int tid = threadIdx.x;
  __shared__ float q[H_];
  __shared__ float sc[T_];
  __shared__ float red[512];
  int len = lens[b];
  q[tid] = (u == 0) ? embedded[((size_t)b * U_ + u) * H_ + tid] : h1_prev[b * H_ + tid];
  __syncthreads();
  int w = tid >> 6, l = tid & 63;
  for (int t = w; t < T_; t += 8) {
    if (t < len) {
      const float* row = enc_proj + ((size_t)b * T_ + t) * H_;
      float acc = 0.f;
#pragma unroll
      for (int i = 0; i < 8; i++) acc += row[l + 64 * i] * q[l + 64 * i];
#pragma unroll
      for (int off = 32; off > 0; off >>= 1) acc += __shfl_xor(acc, off, 64);
      if (l == 0) sc[t] = acc;
    } else {
      if (l == 0) sc[t] = -INFINITY;
    }
  }
  __syncthreads();
  float v = sc[tid];
  red[tid] = v;
  __syncthreads();
  for (int s = 256; s > 0; s >>= 1) { if (tid < s) red[tid] = fmaxf(red[tid], red[tid + s]); __syncthreads(); }
  float mx = red[0];
  __syncthreads();
  float p = expf(v - mx);                        // -inf -> 0
  red[tid] = p;
  __syncthreads();
  for (int s = 256; s > 0; s >>= 1) { if (tid < s) red[tid] += red[tid + s]; __syncthreads(); }
  float inv = 1.f / red[0];
  __syncthreads();
  sc[tid] = p * inv;
  __syncthreads();
  // context: thread = e column, coalesced over lanes
  float acc = 0.f;
  const float* eo = enc_out + (size_t)b * T_ * E_ + tid;
  for (int t = 0; t < len; t++) acc += sc[t] * eo[(size_t)t * E_];
  X[((size_t)b * U_ + u) * (H_ + E_) + H_ + tid] = acc;
}

// ---------------- GRU layer 0: x = [emb | ctx] (K=1024), h (K=512) ----------------
__global__ __launch_bounds__(256) void gru0_step(
    const float* __restrict__ embedded, const float* __restrict__ X,
    const float* __restrict__ h_prev, const float* __restrict__ W_ih,
    const float* __restrict__ W_hh, const float* __restrict__ b_ih,
    const float* __restrict__ b_hh, float* __restrict__ h_next, int u) {
  int j = blockIdx.x;            // output unit 0..511
  int tid = threadIdx.x;
  __shared__ float Wr[1024], Wz[1024], Wn[1024], Vr[512], Vz[512], Vn[512];
  __shared__ float red[4][256];
  for (int k = tid; k < 1024; k += 256) {
    Wr[k] = W_ih[(size_t)j * 1024 + k];
    Wz[k] = W_ih[((size_t)j + 512) * 1024 + k];
    Wn[k] = W_ih[((size_t)j + 1024) * 1024 + k];
  }
  for (int k = tid; k < 512; k += 256) {
    Vr[k] = W_hh[(size_t)j * 512 + k];
    Vz[k] = W_hh[((size_t)j + 512) * 512 + k];
    Vn[k] = W_hh[((size_t)j + 1024) * 512 + k];
  }
  __syncthreads();
  int b = tid >> 3, s = tid & 7;
  const float* xe = embedded + ((size_t)b * U_ + u) * H_;
  const float* xc = X + ((size_t)b * U_ + u) * (H_ + E_);  // k>=512 maps straight to X[row*1024+k]
  float ar = 0, az = 0, ain = 0, ahn = 0;
  int k0 = s * 128;
  if (s < 4) {
    for (int k = k0; k < k0 + 128; k++) { float xv = xe[k]; ar += Wr[k] * xv; az += Wz[k] * xv; ain += Wn[k] * xv; }
  } else {
    for (int k = k0; k < k0 + 128; k++) { float xv = xc[k]; ar += Wr[k] * xv; az += Wz[k] * xv; ain += Wn[k] * xv; }
  }
  const float* hp = h_prev + b * H_;
  for (int k = s * 64; k < s * 64 + 64; k++) { float hv = hp[k]; ar += Vr[k] * hv; az += Vz[k] * hv; ahn += Vn[k] * hv; }
  red[0][tid] = ar; red[1][tid] = az; red[2][tid] = ain; red[3][tid] = ahn;
  __syncthreads();
  if (tid < 32) {
    int bb = tid;
    float r = 0, z = 0, in_ = 0, hn = 0;
    for (int q2 = 0; q2 < 8; q2++) {
      r += red[0][bb * 8 + q2]; z += red[1][bb * 8 + q2];
      in_ += red[2][bb * 8 + q2]; hn += red[3][bb * 8 + q2];
    }
    r += b_ih[j] + b_hh[j];
    z += b_ih[512 + j] + b_hh[512 + j];
    float rg = 1.f / (1.f + expf(-r));
    float zg = 1.f / (1.f + expf(-z));
    float n = tanhf(in_ + b_ih[1024 + j] + rg * (hn + b_hh[1024 + j]));
    h_next[bb * H_ + j] = (1.f - zg) * n + zg * h_prev[bb * H_ + j];
  }
}

// ---------------- GRU layer 1: x = h0_next (K=512); also writes X[:,0:512] ----------------
__global__ __launch_bounds__(256) void gru1_step(
    const float* __restrict__ xin, const float* __restrict__ h_prev,
    const float* __restrict__ W_ih, const float* __restrict__ W_hh,
    const float* __restrict__ b_ih, const float* __restrict__ b_hh,
    float* __restrict__ h_next, float* __restrict__ X, int u) {
  int j = blockIdx.x;
  int tid = threadIdx.x;
  __shared__ float Wr[512], Wz[512], Wn[512], Vr[512], Vz[512], Vn[512];
  __shared__ float red[4][256];
  for (int k = tid; k < 512; k += 256) {
    Wr[k] = W_ih[(size_t)j * 512 + k];
    Wz[k] = W_ih[((size_t)j + 512) * 512 + k];
    Wn[k] = W_ih[((size_t)j + 1024) * 512 + k];
    Vr[k] = W_hh[(size_t)j * 512 + k];
    Vz[k] = W_hh[((size_t)j + 512) * 512 + k];
    Vn[k] = W_hh[((size_t)j + 1024) * 512 + k];
  }
  __syncthreads();
  int b = tid >> 3, s = tid & 7;
  const float* xp = xin + b * H_;
  const float* hp = h_prev + b * H_;
  float ar = 0, az = 0, ain = 0, ahn = 0;
  for (int k = s * 64; k < s * 64 + 64; k++) {
    float xv = xp[k]; ar += Wr[k] * xv; az += Wz[k] * xv; ain += Wn[k] * xv;
    float hv = hp[k]; ar += Vr[k] * hv; az += Vz[k] * hv; ahn += Vn[k] * hv;
  }
  red[0][tid] = ar; red[1][tid] = az; red[2][tid] = ain; red[3][tid] = ahn;
  __syncthreads();
  if (tid < 32) {
    int bb = tid;
    float r = 0, z = 0, in_ = 0, hn = 0;
    for (int q2 = 0; q2 < 8; q2++) {
      r += red[0][bb * 8 + q2]; z += red[1][bb * 8 + q2];
      in_ += red[2][bb * 8 + q2]; hn += red[3][bb * 8 + q2];
    }
    r += b_ih[j] + b_hh[j];
    z += b_ih[512 + j] + b_hh[512 + j];
    float rg = 1.f / (1.f + expf(-r));
    float zg = 1.f / (1.f + expf(-z));
    float n = tanhf(in_ + b_ih[1024 + j] + rg * (hn + b_hh[1024 + j]));
    float ho = (1.f - zg) * n + zg * h_prev[bb * H_ + j];
    h_next[bb * H_ + j] = ho;
    X[((size_t)bb * U_ + u) * (H_ + E_) + j] = ho;
  }
}

extern "C" void kernel_launch(void* const* d_in, const int* in_sizes, int n_in,
                              void* d_out, int out_size, void* d_ws, size_t ws_size,
                              hipStream_t stream) {
  const float* encoder_out  = (const float*)d_in[0];
  const int*   encoder_lens = (const int*)d_in[1];
  const int*   decoder_in   = (const int*)d_in[2];
  const float* emb_table    = (const float*)d_in[3];
  const float* W_attn       = (const float*)d_in[4];
  const float* W_ih0        = (const float*)d_in[5];
  const float* W_hh0        = (const float*)d_in[6];
  const float* b_ih0        = (const float*)d_in[7];
  const float* b_hh0        = (const float*)d_in[8];
  const float* W_ih1        = (const float*)d_in[9];
  const float* W_hh1        = (const float*)d_in[10];
  const float* b_ih1        = (const float*)d_in[11];
  const float* b_hh1        = (const float*)d_in[12];
  const float* W_out        = (const float*)d_in[13];
  const float* b_out        = (const float*)d_in[14];
  float* out = (float*)d_out;

  // ws: X [2048x1024] + h0 ping-pong [2x32x512] + h1 ping-pong [2x32x512]  (~8.65 MB)
  float* X   = (float*)d_ws;
  float* h0b = X + 2097152;
  float* h1b = h0b + 32768;
  // big loop-invariant temps live in the head of d_out (fully overwritten by final GEMM)
  float* enc_proj = out;                 // 8,388,608 floats
  float* embedded = out + 8388608;       // 1,048,576 floats

  // init hidden states (both ping-pong buffers, contiguous 65536 floats)
  zero_kernel<<<256, 256, 0, stream>>>(h0b, 65536);
  embed_kernel<<<B_ * U_, 128, 0, stream>>>(decoder_in, emb_table, embedded);
  // enc_proj[b,t,h] = sum_e encoder_out[b,t,e] * W_attn[h,e]  (M=16384, N=512, K=512)
  gemm_abt<<<dim3(4, 128), 256, 0, stream>>>(encoder_out, W_attn, nullptr, enc_proj, 512, 512);

  for (int u = 0; u < U_; u++) {
    int cur = u & 1, nxt = cur ^ 1;
    attn_step<<<B_, 512, 0, stream>>>(enc_proj, encoder_out, encoder_lens, embedded,
                                      h1b + cur * 16384, X, u);
    gru0_step<<<512, 256, 0, stream>>>(embedded, X, h0b + cur * 16384, W_ih0, W_hh0,
                                       b_ih0, b_hh0, h0b + nxt * 16384, u);
    gru1_step<<<512, 256, 0, stream>>>(h0b + nxt * 16384, h1b + cur * 16384, W_ih1, W_hh1,
                                       b_ih1, b_hh1, h1b + nxt * 16384, X, u);
  }
  // logits: out[(b*U+u)*V + v] = X[row,:] . W_out[v,:] + b_out[v]  (M=2048, N=32000, K=1024)
  gemm_abt<<<dim3(250, 16), 256, 0, stream>>>(X, W_out, b_out, out, V_, 1024);
}